// Round 13
// baseline (98.840 us; speedup 1.0000x reference)
//
#include <hip/hip_runtime.h>
#include <hip/hip_bf16.h>

typedef __attribute__((ext_vector_type(8))) short short8;
typedef __attribute__((ext_vector_type(4))) float f32x4;

#define B_  8
#define L_  2048
#define T_  512
#define DH_ 1024
#define DG_ 768
#define P_  256

__device__ __forceinline__ short f2bf(float x) {
    union { float f; unsigned u; } v; v.f = x;
    unsigned r = v.u + 0x7fffu + ((v.u >> 16) & 1u);
    return (short)(r >> 16);
}

typedef __attribute__((address_space(1))) const void av1_t;
typedef __attribute__((address_space(3))) void av3_t;
__device__ __forceinline__ void gl16(const void* g, void* l) {
    __builtin_amdgcn_global_load_lds((av1_t*)g, (av3_t*)l, 16, 0, 0);
}

// ---------------- shared GEMM body ----------------
// C[M,N] = A[M,K] * B[N,K]^T, 4 waves (2x2), BK=64, gl16 staging for bf16,
// XOR-swizzled LDS. As: BM*64 shorts, Bs: BN*64 shorts, invL: BM floats.
// EPI: 1 = bf16 C*cscale
//      2 = QK: e=mask?0:exp(C); bf16 e + per-row partial sums psum[row][32]
//      3 = PV: f32 C * (1/sum(psum row))
template<int BM, int BN, bool AF32, int EPI>
__device__ __forceinline__ void gemm_body(
    const void* __restrict__ Ap, const short* __restrict__ Bp,
    void* __restrict__ Cp, int M, int N, int K, long sA, long sB, long sC,
    float cscale, const unsigned char* __restrict__ mask,
    float* __restrict__ psum, int bx, int by, int b,
    short* As, short* Bs, float* invL)
{
    constexpr int WM = BM / 2, WN = BN / 2, FM = WM / 16, FN = WN / 16;
    const int m0 = by * BM, n0 = bx * BN;

    const int t = threadIdx.x, w = t >> 6, l = t & 63;
    const int wm = w >> 1, wn = w & 1, rl = l & 15, kg = l >> 4;

    const int srow = t >> 3;
    const int schunk = t & 7;
    const int gchunk = schunk ^ (srow & 7);

    const short* Bg0 = Bp + (long)b * sB + (long)(n0 + srow) * K + gchunk * 8;
    char* AsP = (char*)As + t * 16;
    char* BsP = (char*)Bs + t * 16;

    const int ch0 = ((0 | kg) ^ (rl & 7)) * 16;
    const int ch1 = ((4 | kg) ^ (rl & 7)) * 16;

    if constexpr (EPI == 3) {   // denominators: overlap with first staging
        if (t < BM) {
            const float* pp = psum + ((long)b * M + m0 + t) * 32;
            float s = 0.f;
            #pragma unroll
            for (int j = 0; j < 32; j++) s += pp[j];
            invL[t] = 1.0f / s;
        }
    }

    f32x4 acc[FM][FN];
    #pragma unroll
    for (int mi = 0; mi < FM; mi++)
        #pragma unroll
        for (int ni = 0; ni < FN; ni++)
            acc[mi][ni] = (f32x4){0.f, 0.f, 0.f, 0.f};

    for (int k0 = 0; k0 < K; k0 += 64) {
        if (AF32) {
            #pragma unroll
            for (int j = 0; j < BM / 32; j++) {
                const float* ag = (const float*)Ap + (long)b * sA +
                                  (long)(m0 + j * 32 + srow) * K + k0 + schunk * 8;
                float4 v0 = *(const float4*)ag;
                float4 v1 = *(const float4*)(ag + 4);
                short8 sv;
                sv[0]=f2bf(v0.x); sv[1]=f2bf(v0.y); sv[2]=f2bf(v0.z); sv[3]=f2bf(v0.w);
                sv[4]=f2bf(v1.x); sv[5]=f2bf(v1.y); sv[6]=f2bf(v1.z); sv[7]=f2bf(v1.w);
                *(short8*)&As[(j * 32 + srow) * 64 + (schunk ^ (srow & 7)) * 8] = sv;
            }
        } else {
            const short* Ag0 = (const short*)Ap + (long)b * sA +
                               (long)(m0 + srow) * K + k0 + gchunk * 8;
            #pragma unroll
            for (int j = 0; j < BM / 32; j++)
                gl16(Ag0 + (long)j * 32 * K, AsP + j * 4096);
        }
        #pragma unroll
        for (int j = 0; j < BN / 32; j++)
            gl16(Bg0 + k0 + (long)j * 32 * K, BsP + j * 4096);
        __syncthreads();

        #pragma unroll
        for (int kh = 0; kh < 2; kh++) {
            const int ch = kh ? ch1 : ch0;
            short8 a[FM], bb[FN];
            #pragma unroll
            for (int mi = 0; mi < FM; mi++)
                a[mi] = *(short8*)((char*)&As[(wm * WM + mi * 16 + rl) * 64] + ch);
            #pragma unroll
            for (int ni = 0; ni < FN; ni++)
                bb[ni] = *(short8*)((char*)&Bs[(wn * WN + ni * 16 + rl) * 64] + ch);
            #pragma unroll
            for (int mi = 0; mi < FM; mi++)
                #pragma unroll
                for (int ni = 0; ni < FN; ni++)
                    acc[mi][ni] = __builtin_amdgcn_mfma_f32_16x16x32_bf16(
                        a[mi], bb[ni], acc[mi][ni], 0, 0, 0);
        }
        __syncthreads();
    }

    const int rowb = m0 + wm * WM + kg * 4;

    if constexpr (EPI == 2) {
        float* psL = (float*)As;  // [2][BM]
        float pr[FM][4];
        #pragma unroll
        for (int mi = 0; mi < FM; mi++)
            #pragma unroll
            for (int i = 0; i < 4; i++) pr[mi][i] = 0.f;
        #pragma unroll
        for (int mi = 0; mi < FM; mi++)
            #pragma unroll
            for (int ni = 0; ni < FN; ni++) {
                const int n = n0 + wn * WN + ni * 16 + rl;
                const bool mk = mask[(long)b * N + n] != 0;
                #pragma unroll
                for (int i = 0; i < 4; i++) {
                    const float e = mk ? 0.f : __expf(acc[mi][ni][i]);
                    ((short*)Cp)[(long)b * sC + (long)(rowb + mi * 16 + i) * N + n] = f2bf(e);
                    pr[mi][i] += e;
                }
            }
        #pragma unroll
        for (int off = 1; off < 16; off <<= 1)
            #pragma unroll
            for (int mi = 0; mi < FM; mi++)
                #pragma unroll
                for (int i = 0; i < 4; i++)
                    pr[mi][i] += __shfl_xor(pr[mi][i], off);
        if (rl == 0) {
            #pragma unroll
            for (int mi = 0; mi < FM; mi++)
                #pragma unroll
                for (int i = 0; i < 4; i++)
                    psL[wn * BM + wm * WM + mi * 16 + kg * 4 + i] = pr[mi][i];
        }
        __syncthreads();
        if (t < BM)
            psum[((long)b * M + m0 + t) * 32 + bx] = psL[t] + psL[BM + t];
        return;
    }

    #pragma unroll
    for (int mi = 0; mi < FM; mi++)
        #pragma unroll
        for (int ni = 0; ni < FN; ni++) {
            const int n = n0 + wn * WN + ni * 16 + rl;
            #pragma unroll
            for (int i = 0; i < 4; i++) {
                const long idx = (long)b * sC + (long)(rowb + mi * 16 + i) * N + n;
                if constexpr (EPI == 1)
                    ((short*)Cp)[idx] = f2bf(acc[mi][ni][i] * cscale);
                else  // EPI == 3
                    ((float*)Cp)[idx] = acc[mi][ni][i] *
                                        invL[wm * WM + mi * 16 + kg * 4 + i];
            }
        }
}

// ---------------- transpose bodies ----------------
__device__ __forceinline__ void transpose32_body(
    const float* __restrict__ s, short* __restrict__ d,
    int R, int C, int r0, int c0, float* tile /*32x33*/)
{
    const int x = threadIdx.x & 31, y = threadIdx.x >> 5;
    #pragma unroll
    for (int i = 0; i < 32; i += 8)
        tile[(y + i) * 33 + x] = s[(long)(r0 + y + i) * C + (c0 + x)];
    __syncthreads();
    #pragma unroll
    for (int i = 0; i < 32; i += 8)
        d[(long)(c0 + y + i) * R + (r0 + x)] = f2bf(tile[x * 33 + y + i]);
}

// Vectorized 64x64: float4 reads, short8 writes, conflict-free LDS (R8-proven).
__device__ __forceinline__ void transpose64v_body(
    const float* __restrict__ s, short* __restrict__ d,
    int R, int C, int r0, int c0, float* tile /*64x68*/)
{
    const int t = threadIdx.x;
    const int x4 = t & 15, y = t >> 4;            // chunk 0-15, row-group 0-15
    #pragma unroll
    for (int i = 0; i < 4; i++) {
        const int row = y + i * 16;
        *(float4*)&tile[row * 68 + x4 * 4] =
            *(const float4*)(s + (long)(r0 + row) * C + c0 + x4 * 4);
    }
    __syncthreads();
    const int c = t & 63, g = t >> 6;             // out-row 0-63, group 0-3
    #pragma unroll
    for (int j2 = 0; j2 < 2; j2++) {
        const int grp = g + j2 * 4;               // 8-row group 0-7
        short8 outv;
        #pragma unroll
        for (int e = 0; e < 8; e++)
            outv[e] = f2bf(tile[(grp * 8 + e) * 68 + c]);
        *(short8*)(d + (long)(c0 + c) * R + r0 + grp * 8) = outv;
    }
}

// ---------------- kernels ----------------
// Phase A: both weight transposes. blocks: Wk 32x8=256, Wq 24x8=192.
__global__ __launch_bounds__(256) void k_weights(
    const float* __restrict__ Wk, short* __restrict__ WkT,
    const float* __restrict__ Wq, short* __restrict__ WqT)
{
    __shared__ float tile[32 * 33];
    const int f = blockIdx.x;
    if (f < 256) {
        transpose32_body(Wk, WkT, DH_, P_, (f & 31) * 32, (f >> 5) * 32, tile);
    } else {
        const int f2 = f - 256;
        transpose32_body(Wq, WqT, DG_, P_, (f2 % 24) * 32, (f2 / 24) * 32, tile);
    }
}

// Phase B: Ht transpose FIRST (4096 blocks -> drains early), then Q-proj
// (128), then K-proj (512, finishes last -> Kb maximally L2-warm for k_qk).
// Projections: 32x256 single-pass over H/G (FETCH stays ~75 MB).
__global__ __launch_bounds__(256) void k_phaseB(
    const float* __restrict__ H, const float* __restrict__ G,
    const short* __restrict__ WkT, const short* __restrict__ WqT,
    short* __restrict__ Kb, short* __restrict__ Qb, short* __restrict__ Ht)
{
    __shared__ __align__(16) char smem[4096 + 32768 + 128];  // proj | 64x68 f32
    const int f = blockIdx.x;
    if (f < 4096) {                     // Ht: 32 tx x 16 ty x 8 b
        const int tx = f & 31, ty = (f >> 5) & 15, b = f >> 9;
        transpose64v_body(H + (long)b * L_ * DH_, Ht + (long)b * DH_ * L_,
                          L_, DH_, tx * 64, ty * 64, (float*)smem);
    } else if (f < 4224) {              // Q-proj: 16 by x 8 b
        const int f2 = f - 4096;
        gemm_body<32, 256, true, 1>(
            G, WqT, Qb, T_, P_, DG_, (long)T_ * DG_, 0, (long)T_ * P_,
            0.0625f, nullptr, nullptr, 0, f2 & 15, f2 >> 4,
            (short*)smem, (short*)(smem + 4096), (float*)(smem + 4096 + 32768));
    } else {                            // K-proj: 64 by x 8 b
        const int f3 = f - 4224;
        gemm_body<32, 256, true, 1>(
            H, WkT, Kb, L_, P_, DH_, (long)L_ * DH_, 0, (long)L_ * P_,
            1.0f, nullptr, nullptr, 0, f3 & 63, f3 >> 6,
            (short*)smem, (short*)(smem + 4096), (float*)(smem + 4096 + 32768));
    }
}

// Phase C: e = exp(Q K^T) (mask->0) + row partial sums. 1024 blocks.
__global__ __launch_bounds__(256) void k_qk(
    const short* __restrict__ Qb, const short* __restrict__ Kb,
    short* __restrict__ alpha, const unsigned char* __restrict__ mask,
    float* __restrict__ psum)
{
    __shared__ __align__(16) short As[128 * 64];
    __shared__ __align__(16) short Bs[64 * 64];
    const int gx = gridDim.x, gy = gridDim.y;
    const int nwg = gx * gy * (int)gridDim.z;
    int flat = blockIdx.x + gx * (blockIdx.y + gy * blockIdx.z);
    flat = (flat & 7) * (nwg >> 3) + (flat >> 3);
    const int bx = flat % gx, by = (flat / gx) % gy, b = flat / (gx * gy);
    gemm_body<128, 64, false, 2>(
        Qb, Kb, alpha, T_, L_, P_, (long)T_ * P_, (long)L_ * P_, (long)T_ * L_,
        1.0f, mask, psum, bx, by, b, As, Bs, nullptr);
}

// Phase D: Z = (e @ H) / rowsum(e). 512 blocks.
__global__ __launch_bounds__(256) void k_pv(
    const short* __restrict__ alpha, const short* __restrict__ Ht,
    float* __restrict__ Z, float* __restrict__ psum)
{
    __shared__ __align__(16) short As[128 * 64];
    __shared__ __align__(16) short Bs[64 * 64];
    __shared__ float invL[128];
    const int gx = gridDim.x, gy = gridDim.y;
    const int nwg = gx * gy * (int)gridDim.z;
    int flat = blockIdx.x + gx * (blockIdx.y + gy * blockIdx.z);
    flat = (flat & 7) * (nwg >> 3) + (flat >> 3);
    const int bx = flat % gx, by = (flat / gx) % gy, b = flat / (gx * gy);
    gemm_body<128, 64, false, 3>(
        alpha, Ht, Z, T_, DH_, L_, (long)T_ * L_, (long)DH_ * L_, (long)T_ * DH_,
        1.0f, nullptr, psum, bx, by, b, As, Bs, invL);
}

extern "C" void kernel_launch(void* const* d_in, const int* in_sizes, int n_in,
                              void* d_out, int out_size, void* d_ws, size_t ws_size,
                              hipStream_t stream)
{
    const float* H  = (const float*)d_in[0];
    const float* G  = (const float*)d_in[1];
    const float* Wk = (const float*)d_in[2];
    const float* Wq = (const float*)d_in[3];
    const unsigned char* mask = (const unsigned char*)d_in[4];
    float* Z = (float*)d_out;

    char* ws = (char*)d_ws;
    const long OFF_WKT   = 0;                       // 256x1024 bf16 = 512 KB
    const long OFF_WQT   = 524288;                  // 256x768  bf16 = 384 KB
    const long OFF_HT    = 917504;                  // 8x1024x2048 bf16 = 32 MB
    const long OFF_KB    = OFF_HT + 33554432;       // 8x2048x256 bf16 = 8 MB
    const long OFF_QB    = OFF_KB + 8388608;        // 8x512x256 bf16 = 2 MB
    const long OFF_ALPHA = OFF_QB + 2097152;        // 8x512x2048 bf16 = 16 MB
    const long OFF_PSUM  = OFF_ALPHA + 16777216;    // 8x512x32 f32 = 512 KB
    short* WkT   = (short*)(ws + OFF_WKT);
    short* WqT   = (short*)(ws + OFF_WQT);
    short* Ht    = (short*)(ws + OFF_HT);
    short* Kb    = (short*)(ws + OFF_KB);
    short* Qb    = (short*)(ws + OFF_QB);
    short* alpha = (short*)(ws + OFF_ALPHA);        // unnormalized e = exp(logit)
    float* psum  = (float*)(ws + OFF_PSUM);

    // A: weight transposes (448 blocks)
    k_weights<<<dim3(448), 256, 0, stream>>>(Wk, WkT, Wq, WqT);

    // B: Ht transpose (first) + Q-proj + K-proj (last), one launch (4736)
    k_phaseB<<<dim3(4736), 256, 0, stream>>>(H, G, WkT, WqT, Kb, Qb, Ht);

    // C: QK + exp + partial sums
    k_qk<<<dim3(L_/64, T_/128, B_), 256, 0, stream>>>(Qb, Kb, alpha, mask, psum);

    // D: PV + normalize
    k_pv<<<dim3(DH_/64, T_/128, B_), 256, 0, stream>>>(alpha, Ht, Z, psum);
}

// Round 14
// 93.878 us; speedup vs baseline: 1.0529x; 1.0529x over previous
//
#include <hip/hip_runtime.h>
#include <hip/hip_bf16.h>

typedef __attribute__((ext_vector_type(8))) short short8;
typedef __attribute__((ext_vector_type(4))) short short4v;
typedef __attribute__((ext_vector_type(4))) float f32x4;

#define B_  8
#define L_  2048
#define T_  512
#define DH_ 1024
#define DG_ 768
#define P_  256

__device__ __forceinline__ short f2bf(float x) {
    union { float f; unsigned u; } v; v.f = x;
    unsigned r = v.u + 0x7fffu + ((v.u >> 16) & 1u);
    return (short)(r >> 16);
}

typedef __attribute__((address_space(1))) const void av1_t;
typedef __attribute__((address_space(3))) void av3_t;
__device__ __forceinline__ void gl16(const void* g, void* l) {
    __builtin_amdgcn_global_load_lds((av1_t*)g, (av3_t*)l, 16, 0, 0);
}

// ---------------- shared GEMM body (qk / pv, 256 thr, 4 waves) ----------
// C[M,N] = A[M,K] * B[N,K]^T, BK=64, gl16 staging, XOR-swizzled LDS.
// EPI: 2 = QK: e=mask?0:exp(C); bf16 e + per-row partial sums psum[row][32]
//      3 = PV: f32 C * (1/sum(psum row))
template<int BM, int BN, int EPI>
__device__ __forceinline__ void gemm_body(
    const short* __restrict__ Ap, const short* __restrict__ Bp,
    void* __restrict__ Cp, int M, int N, int K, long sA, long sB, long sC,
    const unsigned char* __restrict__ mask,
    float* __restrict__ psum, int bx, int by, int b,
    short* As, short* Bs, float* invL)
{
    constexpr int WM = BM / 2, WN = BN / 2, FM = WM / 16, FN = WN / 16;
    const int m0 = by * BM, n0 = bx * BN;

    const int t = threadIdx.x, w = t >> 6, l = t & 63;
    const int wm = w >> 1, wn = w & 1, rl = l & 15, kg = l >> 4;

    const int srow = t >> 3;
    const int schunk = t & 7;
    const int gchunk = schunk ^ (srow & 7);

    const short* Ag0 = Ap + (long)b * sA + (long)(m0 + srow) * K + gchunk * 8;
    const short* Bg0 = Bp + (long)b * sB + (long)(n0 + srow) * K + gchunk * 8;
    char* AsP = (char*)As + t * 16;
    char* BsP = (char*)Bs + t * 16;

    const int ch0 = ((0 | kg) ^ (rl & 7)) * 16;
    const int ch1 = ((4 | kg) ^ (rl & 7)) * 16;

    if constexpr (EPI == 3) {   // denominators: overlap with first staging
        if (t < BM) {
            const float* pp = psum + ((long)b * M + m0 + t) * 32;
            float s = 0.f;
            #pragma unroll
            for (int j = 0; j < 32; j++) s += pp[j];
            invL[t] = 1.0f / s;
        }
    }

    f32x4 acc[FM][FN];
    #pragma unroll
    for (int mi = 0; mi < FM; mi++)
        #pragma unroll
        for (int ni = 0; ni < FN; ni++)
            acc[mi][ni] = (f32x4){0.f, 0.f, 0.f, 0.f};

    for (int k0 = 0; k0 < K; k0 += 64) {
        #pragma unroll
        for (int j = 0; j < BM / 32; j++)
            gl16(Ag0 + k0 + (long)j * 32 * K, AsP + j * 4096);
        #pragma unroll
        for (int j = 0; j < BN / 32; j++)
            gl16(Bg0 + k0 + (long)j * 32 * K, BsP + j * 4096);
        __syncthreads();

        #pragma unroll
        for (int kh = 0; kh < 2; kh++) {
            const int ch = kh ? ch1 : ch0;
            short8 a[FM], bb[FN];
            #pragma unroll
            for (int mi = 0; mi < FM; mi++)
                a[mi] = *(short8*)((char*)&As[(wm * WM + mi * 16 + rl) * 64] + ch);
            #pragma unroll
            for (int ni = 0; ni < FN; ni++)
                bb[ni] = *(short8*)((char*)&Bs[(wn * WN + ni * 16 + rl) * 64] + ch);
            #pragma unroll
            for (int mi = 0; mi < FM; mi++)
                #pragma unroll
                for (int ni = 0; ni < FN; ni++)
                    acc[mi][ni] = __builtin_amdgcn_mfma_f32_16x16x32_bf16(
                        a[mi], bb[ni], acc[mi][ni], 0, 0, 0);
        }
        __syncthreads();
    }

    const int rowb = m0 + wm * WM + kg * 4;

    if constexpr (EPI == 2) {
        float* psL = (float*)As;  // [2][BM]
        float pr[FM][4];
        #pragma unroll
        for (int mi = 0; mi < FM; mi++)
            #pragma unroll
            for (int i = 0; i < 4; i++) pr[mi][i] = 0.f;
        #pragma unroll
        for (int mi = 0; mi < FM; mi++)
            #pragma unroll
            for (int ni = 0; ni < FN; ni++) {
                const int n = n0 + wn * WN + ni * 16 + rl;
                const bool mk = mask[(long)b * N + n] != 0;
                #pragma unroll
                for (int i = 0; i < 4; i++) {
                    const float e = mk ? 0.f : __expf(acc[mi][ni][i]);
                    ((short*)Cp)[(long)b * sC + (long)(rowb + mi * 16 + i) * N + n] = f2bf(e);
                    pr[mi][i] += e;
                }
            }
        #pragma unroll
        for (int off = 1; off < 16; off <<= 1)
            #pragma unroll
            for (int mi = 0; mi < FM; mi++)
                #pragma unroll
                for (int i = 0; i < 4; i++)
                    pr[mi][i] += __shfl_xor(pr[mi][i], off);
        if (rl == 0) {
            #pragma unroll
            for (int mi = 0; mi < FM; mi++)
                #pragma unroll
                for (int i = 0; i < 4; i++)
                    psL[wn * BM + wm * WM + mi * 16 + kg * 4 + i] = pr[mi][i];
        }
        __syncthreads();
        if (t < BM)
            psum[((long)b * M + m0 + t) * 32 + bx] = psL[t] + psL[BM + t];
        return;
    }

    #pragma unroll
    for (int mi = 0; mi < FM; mi++)
        #pragma unroll
        for (int ni = 0; ni < FN; ni++) {
            const int n = n0 + wn * WN + ni * 16 + rl;
            #pragma unroll
            for (int i = 0; i < 4; i++) {
                const long idx = (long)b * sC + (long)(rowb + mi * 16 + i) * N + n;
                ((float*)Cp)[idx] = acc[mi][ni][i] *
                                    invL[wm * WM + mi * 16 + kg * 4 + i];
            }
        }
}

// ---------------- 8-wave projection body (512 threads) ----------------
// C = (A_f32 @ B^T) * cscale, BM=32, BN=256, 8 waves 2x4 (WM=16, WN=64,
// FM=1, FN=4). Same tile/LDS/barriers as R7's 4-wave version; 2x waves
// halve the per-wave serial chain and double latency-hiding TLP.
// WRT: emit staged A-tile transpose to Htw[b][dh][l], 4 shorts/thread.
template<bool WRT>
__device__ __forceinline__ void proj8(
    const float* __restrict__ Ap, const short* __restrict__ Bp,
    short* __restrict__ Cp, int M, int K, long sA, long sC,
    float cscale, int by, int b,
    short* As /*32x64*/, short* Bs /*256x64*/, short* __restrict__ Htw)
{
    const int m0 = by * 32;
    const int t = threadIdx.x, w = t >> 6, l = t & 63;
    const int wm = w >> 2, wn = w & 3, rl = l & 15, kg = l >> 4;

    // B staging: 512 threads x 4 gl16 (rows j*64 + srow)
    const int srow = t >> 3;            // 0..63
    const int schunk = t & 7;
    const int gchunk = schunk ^ (srow & 7);
    const short* Bg0 = Bp + (long)srow * K + gchunk * 8;
    char* BsP = (char*)Bs + t * 16;

    // A staging (t<256): rows t>>3 in [0,32)
    const int arow = t >> 3, achunk = t & 7;
    const float* Ag = Ap + (long)b * sA + (long)(m0 + arow) * K + achunk * 8;
    const int asws = (achunk ^ (arow & 7)) * 8;

    const int ch0 = ((0 | kg) ^ (rl & 7)) * 16;
    const int ch1 = ((4 | kg) ^ (rl & 7)) * 16;

    f32x4 acc[4];
    #pragma unroll
    for (int ni = 0; ni < 4; ni++) acc[ni] = (f32x4){0.f, 0.f, 0.f, 0.f};

    for (int k0 = 0; k0 < K; k0 += 64) {
        if (t < 256) {
            float4 v0 = *(const float4*)(Ag + k0);
            float4 v1 = *(const float4*)(Ag + k0 + 4);
            short8 sv;
            sv[0]=f2bf(v0.x); sv[1]=f2bf(v0.y); sv[2]=f2bf(v0.z); sv[3]=f2bf(v0.w);
            sv[4]=f2bf(v1.x); sv[5]=f2bf(v1.y); sv[6]=f2bf(v1.z); sv[7]=f2bf(v1.w);
            *(short8*)&As[arow * 64 + asws] = sv;
        }
        #pragma unroll
        for (int j = 0; j < 4; j++)
            gl16(Bg0 + k0 + (long)j * 64 * K, BsP + j * 8192);
        __syncthreads();

        #pragma unroll
        for (int kh = 0; kh < 2; kh++) {
            const int ch = kh ? ch1 : ch0;
            short8 a = *(short8*)((char*)&As[(wm * 16 + rl) * 64] + ch);
            #pragma unroll
            for (int ni = 0; ni < 4; ni++) {
                short8 bb = *(short8*)((char*)&Bs[(wn * 64 + ni * 16 + rl) * 64] + ch);
                acc[ni] = __builtin_amdgcn_mfma_f32_16x16x32_bf16(a, bb, acc[ni], 0, 0, 0);
            }
        }

        if constexpr (WRT) {
            // As (32 l x 64 dh, swizzled) -> Htw[b][k0+dhl][m0 + q8*4 ..]
            const int dhl = t & 63, q8 = t >> 6;
            short4v hv;
            #pragma unroll
            for (int j = 0; j < 4; j++) {
                const int ll = q8 * 4 + j;
                hv[j] = As[ll * 64 + (((dhl >> 3) ^ (ll & 7)) << 3) + (dhl & 7)];
            }
            *(short4v*)(Htw + (long)b * DH_ * L_ + (long)(k0 + dhl) * L_ +
                        m0 + q8 * 4) = hv;
        }
        __syncthreads();
    }

    const int rowb = m0 + wm * 16 + kg * 4;
    #pragma unroll
    for (int ni = 0; ni < 4; ni++) {
        const int n = wn * 64 + ni * 16 + rl;
        #pragma unroll
        for (int i = 0; i < 4; i++)
            Cp[(long)b * sC + (long)(rowb + i) * P_ + n] = f2bf(acc[ni][i] * cscale);
    }
}

// ---------------- transpose body (weights only) ----------------
__device__ __forceinline__ void transpose32_body(
    const float* __restrict__ s, short* __restrict__ d,
    int R, int C, int r0, int c0, float* tile /*32x33*/)
{
    const int x = threadIdx.x & 31, y = threadIdx.x >> 5;
    #pragma unroll
    for (int i = 0; i < 32; i += 8)
        tile[(y + i) * 33 + x] = s[(long)(r0 + y + i) * C + (c0 + x)];
    __syncthreads();
    #pragma unroll
    for (int i = 0; i < 32; i += 8)
        d[(long)(c0 + y + i) * R + (r0 + x)] = f2bf(tile[x * 33 + y + i]);
}

// ---------------- kernels ----------------
// Phase A: both weight transposes. blocks: Wk 32x8=256, Wq 24x8=192.
__global__ __launch_bounds__(256) void k_weights(
    const float* __restrict__ Wk, short* __restrict__ WkT,
    const float* __restrict__ Wq, short* __restrict__ WqT)
{
    __shared__ float tile[32 * 33];
    const int f = blockIdx.x;
    if (f < 256) {
        transpose32_body(Wk, WkT, DH_, P_, (f & 31) * 32, (f >> 5) * 32, tile);
    } else {
        const int f2 = f - 256;
        transpose32_body(Wq, WqT, DG_, P_, (f2 % 24) * 32, (f2 / 24) * 32, tile);
    }
}

// Phase B: K-proj (+fused Ht, 512 blocks) + Q-proj (128 blocks), 8 waves each.
__global__ __launch_bounds__(512) void k_phaseB(
    const float* __restrict__ H, const float* __restrict__ G,
    const short* __restrict__ WkT, const short* __restrict__ WqT,
    short* __restrict__ Kb, short* __restrict__ Qb, short* __restrict__ Ht)
{
    __shared__ __align__(16) char smem[4096 + 32768];
    short* As = (short*)smem;
    short* Bs = (short*)(smem + 4096);
    const int f = blockIdx.x;
    if (f < 512) {
        proj8<true>(H, WkT, Kb, L_, DH_, (long)L_ * DH_, (long)L_ * P_,
                    1.0f, f & 63, f >> 6, As, Bs, Ht);
    } else {
        const int f2 = f - 512;
        proj8<false>(G, WqT, Qb, T_, DG_, (long)T_ * DG_, (long)T_ * P_,
                     0.0625f, f2 & 15, f2 >> 4, As, Bs, nullptr);
    }
}

// Phase C: e = exp(Q K^T) (mask->0) + row partial sums. 1024 blocks.
__global__ __launch_bounds__(256) void k_qk(
    const short* __restrict__ Qb, const short* __restrict__ Kb,
    short* __restrict__ alpha, const unsigned char* __restrict__ mask,
    float* __restrict__ psum)
{
    __shared__ __align__(16) short As[128 * 64];
    __shared__ __align__(16) short Bs[64 * 64];
    const int gx = gridDim.x, gy = gridDim.y;
    const int nwg = gx * gy * (int)gridDim.z;
    int flat = blockIdx.x + gx * (blockIdx.y + gy * blockIdx.z);
    flat = (flat & 7) * (nwg >> 3) + (flat >> 3);
    const int bx = flat % gx, by = (flat / gx) % gy, b = flat / (gx * gy);
    gemm_body<128, 64, 2>(
        Qb, Kb, alpha, T_, L_, P_, (long)T_ * P_, (long)L_ * P_, (long)T_ * L_,
        mask, psum, bx, by, b, As, Bs, nullptr);
}

// Phase D: Z = (e @ H) / rowsum(e). 512 blocks.
__global__ __launch_bounds__(256) void k_pv(
    const short* __restrict__ alpha, const short* __restrict__ Ht,
    float* __restrict__ Z, float* __restrict__ psum)
{
    __shared__ __align__(16) short As[128 * 64];
    __shared__ __align__(16) short Bs[64 * 64];
    __shared__ float invL[128];
    const int gx = gridDim.x, gy = gridDim.y;
    const int nwg = gx * gy * (int)gridDim.z;
    int flat = blockIdx.x + gx * (blockIdx.y + gy * blockIdx.z);
    flat = (flat & 7) * (nwg >> 3) + (flat >> 3);
    const int bx = flat % gx, by = (flat / gx) % gy, b = flat / (gx * gy);
    gemm_body<128, 64, 3>(
        alpha, Ht, Z, T_, DH_, L_, (long)T_ * L_, (long)DH_ * L_, (long)T_ * DH_,
        nullptr, psum, bx, by, b, As, Bs, invL);
}

extern "C" void kernel_launch(void* const* d_in, const int* in_sizes, int n_in,
                              void* d_out, int out_size, void* d_ws, size_t ws_size,
                              hipStream_t stream)
{
    const float* H  = (const float*)d_in[0];
    const float* G  = (const float*)d_in[1];
    const float* Wk = (const float*)d_in[2];
    const float* Wq = (const float*)d_in[3];
    const unsigned char* mask = (const unsigned char*)d_in[4];
    float* Z = (float*)d_out;

    char* ws = (char*)d_ws;
    const long OFF_WKT   = 0;                       // 256x1024 bf16 = 512 KB
    const long OFF_WQT   = 524288;                  // 256x768  bf16 = 384 KB
    const long OFF_HT    = 917504;                  // 8x1024x2048 bf16 = 32 MB
    const long OFF_KB    = OFF_HT + 33554432;       // 8x2048x256 bf16 = 8 MB
    const long OFF_QB    = OFF_KB + 8388608;        // 8x512x256 bf16 = 2 MB
    const long OFF_ALPHA = OFF_QB + 2097152;        // 8x512x2048 bf16 = 16 MB
    const long OFF_PSUM  = OFF_ALPHA + 16777216;    // 8x512x32 f32 = 512 KB
    short* WkT   = (short*)(ws + OFF_WKT);
    short* WqT   = (short*)(ws + OFF_WQT);
    short* Ht    = (short*)(ws + OFF_HT);
    short* Kb    = (short*)(ws + OFF_KB);
    short* Qb    = (short*)(ws + OFF_QB);
    short* alpha = (short*)(ws + OFF_ALPHA);        // unnormalized e = exp(logit)
    float* psum  = (float*)(ws + OFF_PSUM);

    // A: weight transposes (448 blocks)
    k_weights<<<dim3(448), 256, 0, stream>>>(Wk, WkT, Wq, WqT);

    // B: K-proj (+fused Ht) + Q-proj, 8-wave blocks (640 x 512 thr)
    k_phaseB<<<dim3(640), 512, 0, stream>>>(H, G, WkT, WqT, Kb, Qb, Ht);

    // C: QK + exp + partial sums
    k_qk<<<dim3(L_/64, T_/128, B_), 256, 0, stream>>>(Qb, Kb, alpha, mask, psum);

    // D: PV + normalize
    k_pv<<<dim3(DH_/64, T_/128, B_), 256, 0, stream>>>(alpha, Ht, Z, psum);
}

// Round 15
// 82.680 us; speedup vs baseline: 1.1955x; 1.1354x over previous
//
#include <hip/hip_runtime.h>
#include <hip/hip_bf16.h>

typedef __attribute__((ext_vector_type(8))) short short8;
typedef __attribute__((ext_vector_type(4))) float f32x4;

#define B_  8
#define L_  2048
#define T_  512
#define DH_ 1024
#define DG_ 768
#define P_  256

__device__ __forceinline__ short f2bf(float x) {
    union { float f; unsigned u; } v; v.f = x;
    unsigned r = v.u + 0x7fffu + ((v.u >> 16) & 1u);
    return (short)(r >> 16);
}

typedef __attribute__((address_space(1))) const void av1_t;
typedef __attribute__((address_space(3))) void av3_t;
__device__ __forceinline__ void gl16(const void* g, void* l) {
    __builtin_amdgcn_global_load_lds((av1_t*)g, (av3_t*)l, 16, 0, 0);
}

// ---------------- shared GEMM body ----------------
// C[M,N] = A[M,K] * B[N,K]^T, 4 waves (2x2), BK=64, gl16 staging for bf16,
// XOR-swizzled LDS. As: BM*64 shorts, Bs: BN*64 shorts, invL: BM floats.
// EPI: 1 = bf16 C*cscale
//      2 = QK: e=mask?0:exp(C); bf16 e + per-row partial sums psum[row][32]
//      3 = PV: f32 C * (1/sum(psum row))
// WRT: K-proj fusion — while the f32->bf16 A-tile (32 l x 64 dh) sits in LDS,
//      also emit its transpose to Htw[b][dh][l] (64B segments per dh row).
//      (R7 mapping; its 8-way LDS read conflict measured benign — R11's
//      conflict-free remap was 4us SLOWER overall.)
template<int BM, int BN, bool AF32, int EPI, bool WRT>
__device__ __forceinline__ void gemm_body(
    const void* __restrict__ Ap, const short* __restrict__ Bp,
    void* __restrict__ Cp, int M, int N, int K, long sA, long sB, long sC,
    float cscale, const unsigned char* __restrict__ mask,
    float* __restrict__ psum, int bx, int by, int b,
    short* As, short* Bs, float* invL, short* __restrict__ Htw)
{
    constexpr int WM = BM / 2, WN = BN / 2, FM = WM / 16, FN = WN / 16;
    const int m0 = by * BM, n0 = bx * BN;

    const int t = threadIdx.x, w = t >> 6, l = t & 63;
    const int wm = w >> 1, wn = w & 1, rl = l & 15, kg = l >> 4;

    const int srow = t >> 3;
    const int schunk = t & 7;
    const int gchunk = schunk ^ (srow & 7);

    const short* Bg0 = Bp + (long)b * sB + (long)(n0 + srow) * K + gchunk * 8;
    char* AsP = (char*)As + t * 16;
    char* BsP = (char*)Bs + t * 16;

    const int ch0 = ((0 | kg) ^ (rl & 7)) * 16;
    const int ch1 = ((4 | kg) ^ (rl & 7)) * 16;

    if constexpr (EPI == 3) {   // denominators: overlap with first staging
        if (t < BM) {
            const float* pp = psum + ((long)b * M + m0 + t) * 32;
            float s = 0.f;
            #pragma unroll
            for (int j = 0; j < 32; j++) s += pp[j];
            invL[t] = 1.0f / s;
        }
    }

    f32x4 acc[FM][FN];
    #pragma unroll
    for (int mi = 0; mi < FM; mi++)
        #pragma unroll
        for (int ni = 0; ni < FN; ni++)
            acc[mi][ni] = (f32x4){0.f, 0.f, 0.f, 0.f};

    for (int k0 = 0; k0 < K; k0 += 64) {
        if (AF32) {
            #pragma unroll
            for (int j = 0; j < BM / 32; j++) {
                const float* ag = (const float*)Ap + (long)b * sA +
                                  (long)(m0 + j * 32 + srow) * K + k0 + schunk * 8;
                float4 v0 = *(const float4*)ag;
                float4 v1 = *(const float4*)(ag + 4);
                short8 sv;
                sv[0]=f2bf(v0.x); sv[1]=f2bf(v0.y); sv[2]=f2bf(v0.z); sv[3]=f2bf(v0.w);
                sv[4]=f2bf(v1.x); sv[5]=f2bf(v1.y); sv[6]=f2bf(v1.z); sv[7]=f2bf(v1.w);
                *(short8*)&As[(j * 32 + srow) * 64 + (schunk ^ (srow & 7)) * 8] = sv;
            }
        } else {
            const short* Ag0 = (const short*)Ap + (long)b * sA +
                               (long)(m0 + srow) * K + k0 + gchunk * 8;
            #pragma unroll
            for (int j = 0; j < BM / 32; j++)
                gl16(Ag0 + (long)j * 32 * K, AsP + j * 4096);
        }
        #pragma unroll
        for (int j = 0; j < BN / 32; j++)
            gl16(Bg0 + k0 + (long)j * 32 * K, BsP + j * 4096);
        __syncthreads();

        #pragma unroll
        for (int kh = 0; kh < 2; kh++) {
            const int ch = kh ? ch1 : ch0;
            short8 a[FM], bb[FN];
            #pragma unroll
            for (int mi = 0; mi < FM; mi++)
                a[mi] = *(short8*)((char*)&As[(wm * WM + mi * 16 + rl) * 64] + ch);
            #pragma unroll
            for (int ni = 0; ni < FN; ni++)
                bb[ni] = *(short8*)((char*)&Bs[(wn * WN + ni * 16 + rl) * 64] + ch);
            #pragma unroll
            for (int mi = 0; mi < FM; mi++)
                #pragma unroll
                for (int ni = 0; ni < FN; ni++)
                    acc[mi][ni] = __builtin_amdgcn_mfma_f32_16x16x32_bf16(
                        a[mi], bb[ni], acc[mi][ni], 0, 0, 0);
        }

        if constexpr (WRT) {
            // As (32 l x 64 dh, swizzled) -> Htw[b][k0+dhl][m0 + q*8 ..]
            static_assert(!WRT || BM == 32, "WRT path assumes BM==32");
            const int dhl = t >> 2, q = t & 3;
            short8 hv;
            #pragma unroll
            for (int j = 0; j < 8; j++) {
                const int ll = q * 8 + j;
                hv[j] = As[ll * 64 + (((dhl >> 3) ^ j) << 3) + (dhl & 7)];
            }
            *(short8*)(Htw + (long)b * DH_ * L_ + (long)(k0 + dhl) * L_ +
                       m0 + q * 8) = hv;
        }
        __syncthreads();
    }

    const int rowb = m0 + wm * WM + kg * 4;

    if constexpr (EPI == 2) {
        float* psL = (float*)As;  // [2][BM]
        float pr[FM][4];
        #pragma unroll
        for (int mi = 0; mi < FM; mi++)
            #pragma unroll
            for (int i = 0; i < 4; i++) pr[mi][i] = 0.f;
        #pragma unroll
        for (int mi = 0; mi < FM; mi++)
            #pragma unroll
            for (int ni = 0; ni < FN; ni++) {
                const int n = n0 + wn * WN + ni * 16 + rl;
                const bool mk = mask[(long)b * N + n] != 0;
                #pragma unroll
                for (int i = 0; i < 4; i++) {
                    const float e = mk ? 0.f : __expf(acc[mi][ni][i]);
                    ((short*)Cp)[(long)b * sC + (long)(rowb + mi * 16 + i) * N + n] = f2bf(e);
                    pr[mi][i] += e;
                }
            }
        #pragma unroll
        for (int off = 1; off < 16; off <<= 1)
            #pragma unroll
            for (int mi = 0; mi < FM; mi++)
                #pragma unroll
                for (int i = 0; i < 4; i++)
                    pr[mi][i] += __shfl_xor(pr[mi][i], off);
        if (rl == 0) {
            #pragma unroll
            for (int mi = 0; mi < FM; mi++)
                #pragma unroll
                for (int i = 0; i < 4; i++)
                    psL[wn * BM + wm * WM + mi * 16 + kg * 4 + i] = pr[mi][i];
        }
        __syncthreads();
        if (t < BM)
            psum[((long)b * M + m0 + t) * 32 + bx] = psL[t] + psL[BM + t];
        return;
    }

    #pragma unroll
    for (int mi = 0; mi < FM; mi++)
        #pragma unroll
        for (int ni = 0; ni < FN; ni++) {
            const int n = n0 + wn * WN + ni * 16 + rl;
            #pragma unroll
            for (int i = 0; i < 4; i++) {
                const long idx = (long)b * sC + (long)(rowb + mi * 16 + i) * N + n;
                if constexpr (EPI == 1)
                    ((short*)Cp)[idx] = f2bf(acc[mi][ni][i] * cscale);
                else  // EPI == 3
                    ((float*)Cp)[idx] = acc[mi][ni][i] *
                                        invL[wm * WM + mi * 16 + kg * 4 + i];
            }
        }
}

// ---------------- transpose body (weights only) ----------------
__device__ __forceinline__ void transpose32_body(
    const float* __restrict__ s, short* __restrict__ d,
    int R, int C, int r0, int c0, float* tile /*32x33*/)
{
    const int x = threadIdx.x & 31, y = threadIdx.x >> 5;
    #pragma unroll
    for (int i = 0; i < 32; i += 8)
        tile[(y + i) * 33 + x] = s[(long)(r0 + y + i) * C + (c0 + x)];
    __syncthreads();
    #pragma unroll
    for (int i = 0; i < 32; i += 8)
        d[(long)(c0 + y + i) * R + (r0 + x)] = f2bf(tile[x * 33 + y + i]);
}

// ---------------- kernels ----------------
// Phase A: both weight transposes. blocks: Wk 32x8=256, Wq 24x8=192.
__global__ __launch_bounds__(256) void k_weights(
    const float* __restrict__ Wk, short* __restrict__ WkT,
    const float* __restrict__ Wq, short* __restrict__ WqT)
{
    __shared__ float tile[32 * 33];
    const int f = blockIdx.x;
    if (f < 256) {
        transpose32_body(Wk, WkT, DH_, P_, (f & 31) * 32, (f >> 5) * 32, tile);
    } else {
        const int f2 = f - 256;
        transpose32_body(Wq, WqT, DG_, P_, (f2 % 24) * 32, (f2 / 24) * 32, tile);
    }
}

// Phase B: K-proj with fused Ht emission (512 blocks) + Q-proj (128 blocks).
// 32x256 tiles: H and G read exactly once; Ht written from the staged LDS
// tile between the existing barriers (no extra sync).
__global__ __launch_bounds__(256) void k_phaseB(
    const float* __restrict__ H, const float* __restrict__ G,
    const short* __restrict__ WkT, const short* __restrict__ WqT,
    short* __restrict__ Kb, short* __restrict__ Qb, short* __restrict__ Ht)
{
    __shared__ __align__(16) char smem[4096 + 32768 + 128];
    const int f = blockIdx.x;
    if (f < 512) {
        gemm_body<32, 256, true, 1, true>(
            H, WkT, Kb, L_, P_, DH_, (long)L_ * DH_, 0, (long)L_ * P_,
            1.0f, nullptr, nullptr, 0, f & 63, f >> 6,
            (short*)smem, (short*)(smem + 4096), (float*)(smem + 4096 + 32768), Ht);
    } else {
        const int f2 = f - 512;
        gemm_body<32, 256, true, 1, false>(
            G, WqT, Qb, T_, P_, DG_, (long)T_ * DG_, 0, (long)T_ * P_,
            0.0625f, nullptr, nullptr, 0, f2 & 15, f2 >> 4,
            (short*)smem, (short*)(smem + 4096), (float*)(smem + 4096 + 32768), nullptr);
    }
}

// Phase C: e = exp(Q K^T) (mask->0) + row partial sums. 1024 blocks.
__global__ __launch_bounds__(256) void k_qk(
    const short* __restrict__ Qb, const short* __restrict__ Kb,
    short* __restrict__ alpha, const unsigned char* __restrict__ mask,
    float* __restrict__ psum)
{
    __shared__ __align__(16) short As[128 * 64];
    __shared__ __align__(16) short Bs[64 * 64];
    const int gx = gridDim.x, gy = gridDim.y;
    const int nwg = gx * gy * (int)gridDim.z;
    int flat = blockIdx.x + gx * (blockIdx.y + gy * blockIdx.z);
    flat = (flat & 7) * (nwg >> 3) + (flat >> 3);
    const int bx = flat % gx, by = (flat / gx) % gy, b = flat / (gx * gy);
    gemm_body<128, 64, false, 2, false>(
        Qb, Kb, alpha, T_, L_, P_, (long)T_ * P_, (long)L_ * P_, (long)T_ * L_,
        1.0f, mask, psum, bx, by, b, As, Bs, nullptr, nullptr);
}

// Phase D: Z = (e @ H) / rowsum(e). 512 blocks.
__global__ __launch_bounds__(256) void k_pv(
    const short* __restrict__ alpha, const short* __restrict__ Ht,
    float* __restrict__ Z, float* __restrict__ psum)
{
    __shared__ __align__(16) short As[128 * 64];
    __shared__ __align__(16) short Bs[64 * 64];
    __shared__ float invL[128];
    const int gx = gridDim.x, gy = gridDim.y;
    const int nwg = gx * gy * (int)gridDim.z;
    int flat = blockIdx.x + gx * (blockIdx.y + gy * blockIdx.z);
    flat = (flat & 7) * (nwg >> 3) + (flat >> 3);
    const int bx = flat % gx, by = (flat / gx) % gy, b = flat / (gx * gy);
    gemm_body<128, 64, false, 3, false>(
        alpha, Ht, Z, T_, DH_, L_, (long)T_ * L_, (long)DH_ * L_, (long)T_ * DH_,
        1.0f, nullptr, psum, bx, by, b, As, Bs, invL, nullptr);
}

extern "C" void kernel_launch(void* const* d_in, const int* in_sizes, int n_in,
                              void* d_out, int out_size, void* d_ws, size_t ws_size,
                              hipStream_t stream)
{
    const float* H  = (const float*)d_in[0];
    const float* G  = (const float*)d_in[1];
    const float* Wk = (const float*)d_in[2];
    const float* Wq = (const float*)d_in[3];
    const unsigned char* mask = (const unsigned char*)d_in[4];
    float* Z = (float*)d_out;

    char* ws = (char*)d_ws;
    const long OFF_WKT   = 0;                       // 256x1024 bf16 = 512 KB
    const long OFF_WQT   = 524288;                  // 256x768  bf16 = 384 KB
    const long OFF_HT    = 917504;                  // 8x1024x2048 bf16 = 32 MB
    const long OFF_KB    = OFF_HT + 33554432;       // 8x2048x256 bf16 = 8 MB
    const long OFF_QB    = OFF_KB + 8388608;        // 8x512x256 bf16 = 2 MB
    const long OFF_ALPHA = OFF_QB + 2097152;        // 8x512x2048 bf16 = 16 MB
    const long OFF_PSUM  = OFF_ALPHA + 16777216;    // 8x512x32 f32 = 512 KB
    short* WkT   = (short*)(ws + OFF_WKT);
    short* WqT   = (short*)(ws + OFF_WQT);
    short* Ht    = (short*)(ws + OFF_HT);
    short* Kb    = (short*)(ws + OFF_KB);
    short* Qb    = (short*)(ws + OFF_QB);
    short* alpha = (short*)(ws + OFF_ALPHA);        // unnormalized e = exp(logit)
    float* psum  = (float*)(ws + OFF_PSUM);

    // A: weight transposes (448 blocks)
    k_weights<<<dim3(448), 256, 0, stream>>>(Wk, WkT, Wq, WqT);

    // B: K-proj (+fused Ht) + Q-proj, one launch (640 blocks)
    k_phaseB<<<dim3(640), 256, 0, stream>>>(H, G, WkT, WqT, Kb, Qb, Ht);

    // C: QK + exp + partial sums
    k_qk<<<dim3(L_/64, T_/128, B_), 256, 0, stream>>>(Qb, Kb, alpha, mask, psum);

    // D: PV + normalize
    k_pv<<<dim3(DH_/64, T_/128, B_), 256, 0, stream>>>(alpha, Ht, Z, psum);
}